// Round 7
// baseline (433.929 us; speedup 1.0000x reference)
//
#include <hip/hip_runtime.h>
#include <cstdint>

#define K_NE 16
constexpr int B = 8, N = 2048, F = 128;
constexpr size_t NSEND = (size_t)B * N;                 // 16384 sender rows
constexpr size_t EDGE_FLOATS = NSEND * K_NE * 256;      // 67,108,864
constexpr size_t SEND_FLOATS = (size_t)B * N * N;       // 33,554,432

// ---------------- K0: row norms (one wave per 128-float row) ----------------
__global__ __launch_bounds__(256) void norms_kernel(const float* __restrict__ X,
                                                    float* __restrict__ out) {
    int tid = blockIdx.x * 256 + threadIdx.x;
    int w = tid >> 6, lane = tid & 63;
    const float2 v = ((const float2*)(X + (size_t)w * F))[lane];
    float s = v.x * v.x + v.y * v.y;
    #pragma unroll
    for (int off = 32; off; off >>= 1) s += __shfl_xor(s, off);
    if (lane == 0) out[w] = s;
}

// ---------------- K1: score matrix  dist[b][s][r] = |x2+y2-2*dot| -----------
// v4: NO LDS, NO barriers. Wave = 16 sender rows x 64 receiver cols.
// Lane owns one receiver column, staged in registers (4 phases x 8 float4,
// statically indexed). Sender operands are block-uniform -> scalar (SGPR)
// loads, so the inner op is v_fmac_f32 v_acc, s_send, v_recv: zero DS
// traffic. Per-(r,c) accumulation: single fmaf chain, k ascending ->
// bit-identical to all previous passing versions (selection preserved).
__global__ __launch_bounds__(256) void score_kernel(const float* __restrict__ S,
                                                    const float* __restrict__ Rv,
                                                    const float* __restrict__ x2,
                                                    const float* __restrict__ y2,
                                                    float* __restrict__ scores) {
    const int t    = threadIdx.x;
    const int rowg = blockIdx.y;              // 0..1023, 16 sender rows each
    const int bz   = rowg >> 7;               // batch
    const int row0 = rowg << 4;               // global sender row base
    const int c    = (blockIdx.x << 8) + t;   // receiver col in batch (0..2047)

    const float* __restrict__ srow = S + (size_t)row0 * F;            // uniform
    const float* __restrict__ rcol = Rv + ((size_t)bz * N + c) * F;   // per-lane

    float acc[16];
    #pragma unroll
    for (int r = 0; r < 16; ++r) acc[r] = 0.f;

    for (int kp = 0; kp < 4; ++kp) {          // 4 phases of 32 k
        float4 rb[8];
        #pragma unroll
        for (int f = 0; f < 8; ++f)
            rb[f] = *(const float4*)(rcol + (kp << 5) + (f << 2));
        #pragma unroll
        for (int f = 0; f < 8; ++f) {
            const float4 bb = rb[f];
            #pragma unroll
            for (int r = 0; r < 16; ++r) {
                const float4 s4 = *(const float4*)(srow + r * F + (kp << 5) + (f << 2));
                acc[r] = fmaf(s4.x, bb.x, acc[r]);
                acc[r] = fmaf(s4.y, bb.y, acc[r]);
                acc[r] = fmaf(s4.z, bb.z, acc[r]);
                acc[r] = fmaf(s4.w, bb.w, acc[r]);
            }
        }
    }

    const float yv = y2[bz * N + c];
    float* outp = scores + (size_t)row0 * N + c;
    #pragma unroll
    for (int r = 0; r < 16; ++r) {
        const float xv = x2[row0 + r];        // uniform (scalar load)
        outp[(size_t)r * N] = fabsf((-2.0f * acc[r] + xv) + yv);
    }
}

// ------- K2: fused top-16 + connectivity row + edge rows --------------------
// One wave per sender row. Row staged as u32 keys (float bits, monotone for
// v>=0) in a LANE-PRIVATE LDS slab (no barriers). Lexicographic (key,idx)
// iterative min-extraction == jax stable top_k. Then the wave writes the 0/1
// connectivity row in place of its score row, and its sender's 16 edge rows
// (ascending receiver-index order via ranks).
__global__ __launch_bounds__(256) void topk_fused_kernel(const float* __restrict__ S,
                                                         const float* __restrict__ Rv,
                                                         float* __restrict__ scores,
                                                         float* __restrict__ edges_out) {
    __shared__ uint32_t rowbuf[4][N];     // 32 KB, lane-private slices
    const int t = threadIdx.x;
    const int lane = t & 63;
    const int w = t >> 6;
    const int g = blockIdx.x * 4 + w;     // global sender id 0..16383
    const int bz = g >> 11;               // batch
    uint32_t* lds = rowbuf[w];
    float* srowp = scores + (size_t)g * N;
    const uint4* sr = (const uint4*)srowp;

    // ---- load row -> LDS keys; build per-lane (key, idx) min --------------
    uint32_t mk = 0xFFFFFFFFu, mi = 0;
    #pragma unroll
    for (int jj = 0; jj < 8; ++jj) {
        uint4 u = sr[jj * 64 + lane];
        *(uint4*)(&lds[jj * 256 + lane * 4]) = u;
        const uint32_t base = (uint32_t)(jj * 256 + lane * 4);
        if (u.x < mk) { mk = u.x; mi = base; }
        if (u.y < mk) { mk = u.y; mi = base + 1; }
        if (u.z < mk) { mk = u.z; mi = base + 2; }
        if (u.w < mk) { mk = u.w; mi = base + 3; }
    }

    // ---- 16 extractions: butterfly min + owner delete/rescan --------------
    int ixs[16];
    #pragma unroll
    for (int it = 0; it < 16; ++it) {
        const uint32_t ck = mk, ci = mi;  // pre-butterfly copy (owner test)
        uint32_t gk = mk, gi = mi;
        #pragma unroll
        for (int off = 32; off; off >>= 1) {
            uint32_t ok = (uint32_t)__shfl_xor((int)gk, off);
            uint32_t oi = (uint32_t)__shfl_xor((int)gi, off);
            if (ok < gk || (ok == gk && oi < gi)) { gk = ok; gi = oi; }
        }
        ixs[it] = (int)gi;
        if (ck == gk && ci == gi) {       // unique owner lane
            lds[gi] = 0xFFFFFFFFu;        // delete
            mk = 0xFFFFFFFFu; mi = 0;     // rescan own 32 slots
            #pragma unroll
            for (int jj = 0; jj < 8; ++jj) {
                uint4 u = *(const uint4*)(&lds[jj * 256 + lane * 4]);
                const uint32_t base = (uint32_t)(jj * 256 + lane * 4);
                if (u.x < mk) { mk = u.x; mi = base; }
                if (u.y < mk) { mk = u.y; mi = base + 1; }
                if (u.z < mk) { mk = u.z; mi = base + 2; }
                if (u.w < mk) { mk = u.w; mi = base + 3; }
            }
        }
    }

    // ---- ranks: output slot = ascending receiver-index position -----------
    int rank[16];
    #pragma unroll
    for (int e = 0; e < 16; ++e) {
        int r = 0;
        #pragma unroll
        for (int f = 0; f < 16; ++f) r += (ixs[f] < ixs[e]) ? 1 : 0;
        rank[e] = r;
    }

    // ---- connectivity row (overwrites this wave's score row) --------------
    uint32_t mask = 0;
    #pragma unroll
    for (int e = 0; e < 16; ++e) {
        const int ix = ixs[e];
        const int lane_t = (ix >> 2) & 63;
        const int bitpos = ((ix >> 8) << 2) | (ix & 3);
        if (lane == lane_t) mask |= (1u << bitpos);
    }
    #pragma unroll
    for (int j = 0; j < 8; ++j) {
        float4 v;
        v.x = (mask >> (j * 4 + 0)) & 1u ? 1.f : 0.f;
        v.y = (mask >> (j * 4 + 1)) & 1u ? 1.f : 0.f;
        v.z = (mask >> (j * 4 + 2)) & 1u ? 1.f : 0.f;
        v.w = (mask >> (j * 4 + 3)) & 1u ? 1.f : 0.f;
        *(float4*)(srowp + j * 256 + lane * 4) = v;
    }

    // ---- edge rows: [sender_feat(128) | recv_feat(128)] -------------------
    const float* srow = S + (size_t)g * F;
    const float* rb = Rv + (size_t)bz * N * F;
    float4 vs = {0.f, 0.f, 0.f, 0.f};
    if (lane < 32) vs = *(const float4*)(srow + lane * 4);
    #pragma unroll
    for (int e = 0; e < 16; ++e) {
        float4 v = vs;
        if (lane >= 32)
            v = *(const float4*)(rb + (size_t)ixs[e] * F + (lane - 32) * 4);
        *(float4*)(edges_out + ((size_t)g * K_NE + rank[e]) * 256 + lane * 4) = v;
    }
}

extern "C" void kernel_launch(void* const* d_in, const int* in_sizes, int n_in,
                              void* d_out, int out_size, void* d_ws, size_t ws_size,
                              hipStream_t stream) {
    (void)in_sizes; (void)n_in; (void)out_size; (void)ws_size;
    const float* recv = (const float*)d_in[0];
    const float* send = (const float*)d_in[1];
    float* out = (float*)d_out;
    float* sender_mat = out + EDGE_FLOATS;       // score scratch, then conn matrix
    float* x2 = (float*)((char*)d_ws + (262144u * 4));
    float* y2 = x2 + NSEND;

    norms_kernel<<<4096, 256, 0, stream>>>(send, x2);
    norms_kernel<<<4096, 256, 0, stream>>>(recv, y2);
    dim3 g1(8, 1024);                            // col-tiles x (16-row groups)
    score_kernel<<<g1, 256, 0, stream>>>(send, recv, x2, y2, sender_mat);
    topk_fused_kernel<<<4096, 256, 0, stream>>>(send, recv, sender_mat, out);
}

// Round 8
// 285.202 us; speedup vs baseline: 1.5215x; 1.5215x over previous
//
#include <hip/hip_runtime.h>
#include <cstdint>

#define K_NE 16
constexpr int B = 8, N = 2048, F = 128;
constexpr size_t NSEND = (size_t)B * N;                 // 16384 sender rows
constexpr size_t EDGE_FLOATS = NSEND * K_NE * 256;      // 67,108,864
constexpr size_t SEND_FLOATS = (size_t)B * N * N;       // 33,554,432

// ---------------- K0: row norms (one wave per 128-float row) ----------------
__global__ __launch_bounds__(256) void norms_kernel(const float* __restrict__ X,
                                                    float* __restrict__ out) {
    int tid = blockIdx.x * 256 + threadIdx.x;
    int w = tid >> 6, lane = tid & 63;
    const float2 v = ((const float2*)(X + (size_t)w * F))[lane];
    float s = v.x * v.x + v.y * v.y;
    #pragma unroll
    for (int off = 32; off; off >>= 1) s += __shfl_xor(s, off);
    if (lane == 0) out[w] = s;
}

// ---------------- K1: score matrix  dist[b][s][r] = |x2+y2-2*dot| -----------
// v5: 128(rows) x 256(cols) block tile, 256 threads, 8x16 micro-tile.
// 24 LDS floats per 128 FMA -> DS:VALU ~1.13 (was 1.5 at 8x8).
// BK=8 k-major LDS, double-buffered (one barrier/chunk) + register prefetch.
// Per-(r,c) accumulation: single fmaf chain, k ascending -> bit-identical
// to all previous passing versions (selection preserved).
__global__ __launch_bounds__(256) void score_kernel(const float* __restrict__ S,
                                                    const float* __restrict__ Rv,
                                                    const float* __restrict__ x2,
                                                    const float* __restrict__ y2,
                                                    float* __restrict__ scores) {
    __shared__ float As[2][8][128];   // [buf][k][row]   8 KB
    __shared__ float Bs[2][8][256];   // [buf][k][col]  16 KB
    const int bx = blockIdx.x, by = blockIdx.y, bz = blockIdx.z;
    const int t = threadIdx.x;
    const int tx = t & 15, ty = t >> 4;
    const float* Sb = S  + (size_t)bz * N * F + (size_t)by * 128 * F;
    const float* Rb = Rv + (size_t)bz * N * F + (size_t)bx * 256 * F;

    const int arow = t >> 1;            // 0..127
    const int kq   = (t & 1) << 2;      // 0 or 4
    const float* pa  = Sb + (size_t)arow * F + kq;
    const float* pb0 = Rb + (size_t)arow * F + kq;          // col arow
    const float* pb1 = Rb + (size_t)(arow + 128) * F + kq;  // col arow+128

    float4 a  = *(const float4*)(pa);
    float4 b0 = *(const float4*)(pb0);
    float4 b1 = *(const float4*)(pb1);
    As[0][kq + 0][arow] = a.x;  As[0][kq + 1][arow] = a.y;
    As[0][kq + 2][arow] = a.z;  As[0][kq + 3][arow] = a.w;
    Bs[0][kq + 0][arow] = b0.x; Bs[0][kq + 1][arow] = b0.y;
    Bs[0][kq + 2][arow] = b0.z; Bs[0][kq + 3][arow] = b0.w;
    Bs[0][kq + 0][128 + arow] = b1.x; Bs[0][kq + 1][128 + arow] = b1.y;
    Bs[0][kq + 2][128 + arow] = b1.z; Bs[0][kq + 3][128 + arow] = b1.w;
    __syncthreads();

    float acc[8][16] = {};

    for (int kc = 0; kc < 16; ++kc) {   // 16 chunks of BK=8
        const int cur = kc & 1;
        if (kc < 15) {                  // issue next chunk's loads early
            const int o = (kc + 1) << 3;
            a  = *(const float4*)(pa + o);
            b0 = *(const float4*)(pb0 + o);
            b1 = *(const float4*)(pb1 + o);
        }
        #pragma unroll
        for (int k = 0; k < 8; ++k) {
            const float4 af0 = *(const float4*)(&As[cur][k][ty * 4]);
            const float4 af1 = *(const float4*)(&As[cur][k][64 + ty * 4]);
            const float4 bf0 = *(const float4*)(&Bs[cur][k][tx * 4]);
            const float4 bf1 = *(const float4*)(&Bs[cur][k][64 + tx * 4]);
            const float4 bf2 = *(const float4*)(&Bs[cur][k][128 + tx * 4]);
            const float4 bf3 = *(const float4*)(&Bs[cur][k][192 + tx * 4]);
            const float av[8]  = {af0.x, af0.y, af0.z, af0.w,
                                  af1.x, af1.y, af1.z, af1.w};
            const float bv[16] = {bf0.x, bf0.y, bf0.z, bf0.w,
                                  bf1.x, bf1.y, bf1.z, bf1.w,
                                  bf2.x, bf2.y, bf2.z, bf2.w,
                                  bf3.x, bf3.y, bf3.z, bf3.w};
            #pragma unroll
            for (int i = 0; i < 8; ++i)
                #pragma unroll
                for (int j = 0; j < 16; ++j)
                    acc[i][j] = fmaf(av[i], bv[j], acc[i][j]);
        }
        if (kc < 15) {
            const int nxt = cur ^ 1;    // write next buffer; one barrier/chunk
            As[nxt][kq + 0][arow] = a.x;  As[nxt][kq + 1][arow] = a.y;
            As[nxt][kq + 2][arow] = a.z;  As[nxt][kq + 3][arow] = a.w;
            Bs[nxt][kq + 0][arow] = b0.x; Bs[nxt][kq + 1][arow] = b0.y;
            Bs[nxt][kq + 2][arow] = b0.z; Bs[nxt][kq + 3][arow] = b0.w;
            Bs[nxt][kq + 0][128 + arow] = b1.x; Bs[nxt][kq + 1][128 + arow] = b1.y;
            Bs[nxt][kq + 2][128 + arow] = b1.z; Bs[nxt][kq + 3][128 + arow] = b1.w;
            __syncthreads();
        }
    }

    float* outb = scores + (size_t)bz * N * N;
    const float* x2b = x2 + (size_t)bz * N;
    const float* y2b = y2 + (size_t)bz * N;
    float yv[16];
    #pragma unroll
    for (int j = 0; j < 16; ++j)
        yv[j] = y2b[bx * 256 + tx * 4 + (j & 3) + 64 * (j >> 2)];
    #pragma unroll
    for (int i = 0; i < 8; ++i) {
        const int r = by * 128 + ty * 4 + (i & 3) + 64 * (i >> 2);
        const float xv = x2b[r];
        float* orow = outb + (size_t)r * N + bx * 256;
        #pragma unroll
        for (int q = 0; q < 4; ++q) {
            float4 o;
            o.x = fabsf((-2.0f * acc[i][q * 4 + 0] + xv) + yv[q * 4 + 0]);
            o.y = fabsf((-2.0f * acc[i][q * 4 + 1] + xv) + yv[q * 4 + 1]);
            o.z = fabsf((-2.0f * acc[i][q * 4 + 2] + xv) + yv[q * 4 + 2]);
            o.w = fabsf((-2.0f * acc[i][q * 4 + 3] + xv) + yv[q * 4 + 3]);
            *(float4*)(orow + 64 * q + tx * 4) = o;
        }
    }
}

// ------- K2: fused top-16 + connectivity row + edge rows --------------------
// One wave per sender row. Row staged as u32 keys (float bits, monotone for
// v>=0) in a LANE-PRIVATE LDS slab (no barriers). Lexicographic (key,idx)
// iterative min-extraction == jax stable top_k. Then the wave writes the 0/1
// connectivity row in place of its score row, and its sender's 16 edge rows
// (ascending receiver-index order via ranks).
__global__ __launch_bounds__(256) void topk_fused_kernel(const float* __restrict__ S,
                                                         const float* __restrict__ Rv,
                                                         float* __restrict__ scores,
                                                         float* __restrict__ edges_out) {
    __shared__ uint32_t rowbuf[4][N];     // 32 KB, lane-private slices
    const int t = threadIdx.x;
    const int lane = t & 63;
    const int w = t >> 6;
    const int g = blockIdx.x * 4 + w;     // global sender id 0..16383
    const int bz = g >> 11;               // batch
    uint32_t* lds = rowbuf[w];
    float* srowp = scores + (size_t)g * N;
    const uint4* sr = (const uint4*)srowp;

    // ---- load row -> LDS keys; build per-lane (key, idx) min --------------
    uint32_t mk = 0xFFFFFFFFu, mi = 0;
    #pragma unroll
    for (int jj = 0; jj < 8; ++jj) {
        uint4 u = sr[jj * 64 + lane];
        *(uint4*)(&lds[jj * 256 + lane * 4]) = u;
        const uint32_t base = (uint32_t)(jj * 256 + lane * 4);
        if (u.x < mk) { mk = u.x; mi = base; }
        if (u.y < mk) { mk = u.y; mi = base + 1; }
        if (u.z < mk) { mk = u.z; mi = base + 2; }
        if (u.w < mk) { mk = u.w; mi = base + 3; }
    }

    // ---- 16 extractions: butterfly min + owner delete/rescan --------------
    int ixs[16];
    #pragma unroll
    for (int it = 0; it < 16; ++it) {
        const uint32_t ck = mk, ci = mi;  // pre-butterfly copy (owner test)
        uint32_t gk = mk, gi = mi;
        #pragma unroll
        for (int off = 32; off; off >>= 1) {
            uint32_t ok = (uint32_t)__shfl_xor((int)gk, off);
            uint32_t oi = (uint32_t)__shfl_xor((int)gi, off);
            if (ok < gk || (ok == gk && oi < gi)) { gk = ok; gi = oi; }
        }
        ixs[it] = (int)gi;
        if (ck == gk && ci == gi) {       // unique owner lane
            lds[gi] = 0xFFFFFFFFu;        // delete
            mk = 0xFFFFFFFFu; mi = 0;     // rescan own 32 slots
            #pragma unroll
            for (int jj = 0; jj < 8; ++jj) {
                uint4 u = *(const uint4*)(&lds[jj * 256 + lane * 4]);
                const uint32_t base = (uint32_t)(jj * 256 + lane * 4);
                if (u.x < mk) { mk = u.x; mi = base; }
                if (u.y < mk) { mk = u.y; mi = base + 1; }
                if (u.z < mk) { mk = u.z; mi = base + 2; }
                if (u.w < mk) { mk = u.w; mi = base + 3; }
            }
        }
    }

    // ---- ranks: output slot = ascending receiver-index position -----------
    int rank[16];
    #pragma unroll
    for (int e = 0; e < 16; ++e) {
        int r = 0;
        #pragma unroll
        for (int f = 0; f < 16; ++f) r += (ixs[f] < ixs[e]) ? 1 : 0;
        rank[e] = r;
    }

    // ---- connectivity row (overwrites this wave's score row) --------------
    uint32_t mask = 0;
    #pragma unroll
    for (int e = 0; e < 16; ++e) {
        const int ix = ixs[e];
        const int lane_t = (ix >> 2) & 63;
        const int bitpos = ((ix >> 8) << 2) | (ix & 3);
        if (lane == lane_t) mask |= (1u << bitpos);
    }
    #pragma unroll
    for (int j = 0; j < 8; ++j) {
        float4 v;
        v.x = (mask >> (j * 4 + 0)) & 1u ? 1.f : 0.f;
        v.y = (mask >> (j * 4 + 1)) & 1u ? 1.f : 0.f;
        v.z = (mask >> (j * 4 + 2)) & 1u ? 1.f : 0.f;
        v.w = (mask >> (j * 4 + 3)) & 1u ? 1.f : 0.f;
        *(float4*)(srowp + j * 256 + lane * 4) = v;
    }

    // ---- edge rows: [sender_feat(128) | recv_feat(128)] -------------------
    const float* srow = S + (size_t)g * F;
    const float* rb = Rv + (size_t)bz * N * F;
    float4 vs = {0.f, 0.f, 0.f, 0.f};
    if (lane < 32) vs = *(const float4*)(srow + lane * 4);
    #pragma unroll
    for (int e = 0; e < 16; ++e) {
        float4 v = vs;
        if (lane >= 32)
            v = *(const float4*)(rb + (size_t)ixs[e] * F + (lane - 32) * 4);
        *(float4*)(edges_out + ((size_t)g * K_NE + rank[e]) * 256 + lane * 4) = v;
    }
}

extern "C" void kernel_launch(void* const* d_in, const int* in_sizes, int n_in,
                              void* d_out, int out_size, void* d_ws, size_t ws_size,
                              hipStream_t stream) {
    (void)in_sizes; (void)n_in; (void)out_size; (void)ws_size;
    const float* recv = (const float*)d_in[0];
    const float* send = (const float*)d_in[1];
    float* out = (float*)d_out;
    float* sender_mat = out + EDGE_FLOATS;       // score scratch, then conn matrix
    float* x2 = (float*)((char*)d_ws + (262144u * 4));
    float* y2 = x2 + NSEND;

    norms_kernel<<<4096, 256, 0, stream>>>(send, x2);
    norms_kernel<<<4096, 256, 0, stream>>>(recv, y2);
    dim3 g1(8, 16, 8);                           // 256-col tiles, 128-row tiles
    score_kernel<<<g1, 256, 0, stream>>>(send, recv, x2, y2, sender_mat);
    topk_fused_kernel<<<4096, 256, 0, stream>>>(send, recv, sender_mat, out);
}

// Round 9
// 269.059 us; speedup vs baseline: 1.6128x; 1.0600x over previous
//
#include <hip/hip_runtime.h>
#include <cstdint>

#define K_NE 16
constexpr int B = 8, N = 2048, F = 128;
constexpr size_t NSEND = (size_t)B * N;                 // 16384 sender rows
constexpr size_t EDGE_FLOATS = NSEND * K_NE * 256;      // 67,108,864
constexpr size_t SEND_FLOATS = (size_t)B * N * N;       // 33,554,432

// ---------------- K0: row norms (one wave per 128-float row) ----------------
__global__ __launch_bounds__(256) void norms_kernel(const float* __restrict__ X,
                                                    float* __restrict__ out) {
    int tid = blockIdx.x * 256 + threadIdx.x;
    int w = tid >> 6, lane = tid & 63;
    const float2 v = ((const float2*)(X + (size_t)w * F))[lane];
    float s = v.x * v.x + v.y * v.y;
    #pragma unroll
    for (int off = 32; off; off >>= 1) s += __shfl_xor(s, off);
    if (lane == 0) out[w] = s;
}

// ---------------- K1: score matrix  dist[b][s][r] = |x2+y2-2*dot| -----------
// v6: 128x128 tile, 256 threads, 8x8 micro-tile (~110 VGPR sweet spot),
// BK=16 k-major LDS double-buffered: 8 chunks -> 8 barriers (was 16).
// NO launch_bounds occupancy cap (r3 spill trap). Per-(r,c) accumulation:
// single fmaf chain, k = kc*16+k ascending 0..127 -> bit-identical scores
// to all previous passing versions (selection preserved).
__global__ __launch_bounds__(256) void score_kernel(const float* __restrict__ S,
                                                    const float* __restrict__ Rv,
                                                    const float* __restrict__ x2,
                                                    const float* __restrict__ y2,
                                                    float* __restrict__ scores) {
    __shared__ float As[2][16][128];   // [buf][k][row]  16 KB
    __shared__ float Bs[2][16][128];   // [buf][k][col]  16 KB
    const int bx = blockIdx.x, by = blockIdx.y, bz = blockIdx.z;
    const int t = threadIdx.x;
    const int tx = t & 15, ty = t >> 4;
    const float* Sb = S  + (size_t)bz * N * F + (size_t)by * 128 * F;
    const float* Rb = Rv + (size_t)bz * N * F + (size_t)bx * 128 * F;

    const int arow = t >> 1;            // 0..127
    const int kh   = (t & 1) << 3;      // 0 or 8 (k-half within BK=16)
    const float* pa = Sb + (size_t)arow * F + kh;
    const float* pb = Rb + (size_t)arow * F + kh;

    float4 a0 = *(const float4*)(pa);
    float4 a1 = *(const float4*)(pa + 4);
    float4 b0 = *(const float4*)(pb);
    float4 b1 = *(const float4*)(pb + 4);
    As[0][kh + 0][arow] = a0.x; As[0][kh + 1][arow] = a0.y;
    As[0][kh + 2][arow] = a0.z; As[0][kh + 3][arow] = a0.w;
    As[0][kh + 4][arow] = a1.x; As[0][kh + 5][arow] = a1.y;
    As[0][kh + 6][arow] = a1.z; As[0][kh + 7][arow] = a1.w;
    Bs[0][kh + 0][arow] = b0.x; Bs[0][kh + 1][arow] = b0.y;
    Bs[0][kh + 2][arow] = b0.z; Bs[0][kh + 3][arow] = b0.w;
    Bs[0][kh + 4][arow] = b1.x; Bs[0][kh + 5][arow] = b1.y;
    Bs[0][kh + 6][arow] = b1.z; Bs[0][kh + 7][arow] = b1.w;
    __syncthreads();

    float acc[8][8] = {};

    for (int kc = 0; kc < 8; ++kc) {    // 8 chunks of BK=16
        const int cur = kc & 1;
        if (kc < 7) {                   // issue next chunk's loads early
            const int o = (kc + 1) << 4;
            a0 = *(const float4*)(pa + o);
            a1 = *(const float4*)(pa + o + 4);
            b0 = *(const float4*)(pb + o);
            b1 = *(const float4*)(pb + o + 4);
        }
        #pragma unroll
        for (int k = 0; k < 16; ++k) {
            const float4 af0 = *(const float4*)(&As[cur][k][ty * 4]);
            const float4 af1 = *(const float4*)(&As[cur][k][64 + ty * 4]);
            const float4 bf0 = *(const float4*)(&Bs[cur][k][tx * 4]);
            const float4 bf1 = *(const float4*)(&Bs[cur][k][64 + tx * 4]);
            const float av[8] = {af0.x, af0.y, af0.z, af0.w, af1.x, af1.y, af1.z, af1.w};
            const float bv[8] = {bf0.x, bf0.y, bf0.z, bf0.w, bf1.x, bf1.y, bf1.z, bf1.w};
            #pragma unroll
            for (int i = 0; i < 8; ++i)
                #pragma unroll
                for (int j = 0; j < 8; ++j)
                    acc[i][j] = fmaf(av[i], bv[j], acc[i][j]);
        }
        if (kc < 7) {
            const int nxt = cur ^ 1;    // write next buffer; one barrier/chunk
            As[nxt][kh + 0][arow] = a0.x; As[nxt][kh + 1][arow] = a0.y;
            As[nxt][kh + 2][arow] = a0.z; As[nxt][kh + 3][arow] = a0.w;
            As[nxt][kh + 4][arow] = a1.x; As[nxt][kh + 5][arow] = a1.y;
            As[nxt][kh + 6][arow] = a1.z; As[nxt][kh + 7][arow] = a1.w;
            Bs[nxt][kh + 0][arow] = b0.x; Bs[nxt][kh + 1][arow] = b0.y;
            Bs[nxt][kh + 2][arow] = b0.z; Bs[nxt][kh + 3][arow] = b0.w;
            Bs[nxt][kh + 4][arow] = b1.x; Bs[nxt][kh + 5][arow] = b1.y;
            Bs[nxt][kh + 6][arow] = b1.z; Bs[nxt][kh + 7][arow] = b1.w;
            __syncthreads();
        }
    }

    float* outb = scores + (size_t)bz * N * N;
    const float* x2b = x2 + (size_t)bz * N;
    const float* y2b = y2 + (size_t)bz * N;
    float yv[8];
    #pragma unroll
    for (int c = 0; c < 4; ++c) {
        yv[c]     = y2b[bx * 128 + tx * 4 + c];
        yv[4 + c] = y2b[bx * 128 + 64 + tx * 4 + c];
    }
    #pragma unroll
    for (int i = 0; i < 8; ++i) {
        const int r = by * 128 + ty * 4 + (i & 3) + 64 * (i >> 2);
        const float xv = x2b[r];
        float* orow = outb + (size_t)r * N + bx * 128;
        float4 o0, o1;
        o0.x = fabsf((-2.0f * acc[i][0] + xv) + yv[0]);
        o0.y = fabsf((-2.0f * acc[i][1] + xv) + yv[1]);
        o0.z = fabsf((-2.0f * acc[i][2] + xv) + yv[2]);
        o0.w = fabsf((-2.0f * acc[i][3] + xv) + yv[3]);
        o1.x = fabsf((-2.0f * acc[i][4] + xv) + yv[4]);
        o1.y = fabsf((-2.0f * acc[i][5] + xv) + yv[5]);
        o1.z = fabsf((-2.0f * acc[i][6] + xv) + yv[6]);
        o1.w = fabsf((-2.0f * acc[i][7] + xv) + yv[7]);
        *(float4*)(orow + tx * 4)      = o0;
        *(float4*)(orow + 64 + tx * 4) = o1;
    }
}

// ------- K2: fused top-16 + connectivity row + edge rows --------------------
// One wave per sender row. Row staged as u32 keys (float bits, monotone for
// v>=0) in a LANE-PRIVATE LDS slab (no barriers). Lexicographic (key,idx)
// iterative min-extraction == jax stable top_k. Then the wave writes the 0/1
// connectivity row in place of its score row, and its sender's 16 edge rows
// (ascending receiver-index order via ranks).
__global__ __launch_bounds__(256) void topk_fused_kernel(const float* __restrict__ S,
                                                         const float* __restrict__ Rv,
                                                         float* __restrict__ scores,
                                                         float* __restrict__ edges_out) {
    __shared__ uint32_t rowbuf[4][N];     // 32 KB, lane-private slices
    const int t = threadIdx.x;
    const int lane = t & 63;
    const int w = t >> 6;
    const int g = blockIdx.x * 4 + w;     // global sender id 0..16383
    const int bz = g >> 11;               // batch
    uint32_t* lds = rowbuf[w];
    float* srowp = scores + (size_t)g * N;
    const uint4* sr = (const uint4*)srowp;

    // ---- load row -> LDS keys; build per-lane (key, idx) min --------------
    uint32_t mk = 0xFFFFFFFFu, mi = 0;
    #pragma unroll
    for (int jj = 0; jj < 8; ++jj) {
        uint4 u = sr[jj * 64 + lane];
        *(uint4*)(&lds[jj * 256 + lane * 4]) = u;
        const uint32_t base = (uint32_t)(jj * 256 + lane * 4);
        if (u.x < mk) { mk = u.x; mi = base; }
        if (u.y < mk) { mk = u.y; mi = base + 1; }
        if (u.z < mk) { mk = u.z; mi = base + 2; }
        if (u.w < mk) { mk = u.w; mi = base + 3; }
    }

    // ---- 16 extractions: butterfly min + owner delete/rescan --------------
    int ixs[16];
    #pragma unroll
    for (int it = 0; it < 16; ++it) {
        const uint32_t ck = mk, ci = mi;  // pre-butterfly copy (owner test)
        uint32_t gk = mk, gi = mi;
        #pragma unroll
        for (int off = 32; off; off >>= 1) {
            uint32_t ok = (uint32_t)__shfl_xor((int)gk, off);
            uint32_t oi = (uint32_t)__shfl_xor((int)gi, off);
            if (ok < gk || (ok == gk && oi < gi)) { gk = ok; gi = oi; }
        }
        ixs[it] = (int)gi;
        if (ck == gk && ci == gi) {       // unique owner lane
            lds[gi] = 0xFFFFFFFFu;        // delete
            mk = 0xFFFFFFFFu; mi = 0;     // rescan own 32 slots
            #pragma unroll
            for (int jj = 0; jj < 8; ++jj) {
                uint4 u = *(const uint4*)(&lds[jj * 256 + lane * 4]);
                const uint32_t base = (uint32_t)(jj * 256 + lane * 4);
                if (u.x < mk) { mk = u.x; mi = base; }
                if (u.y < mk) { mk = u.y; mi = base + 1; }
                if (u.z < mk) { mk = u.z; mi = base + 2; }
                if (u.w < mk) { mk = u.w; mi = base + 3; }
            }
        }
    }

    // ---- ranks: output slot = ascending receiver-index position -----------
    int rank[16];
    #pragma unroll
    for (int e = 0; e < 16; ++e) {
        int r = 0;
        #pragma unroll
        for (int f = 0; f < 16; ++f) r += (ixs[f] < ixs[e]) ? 1 : 0;
        rank[e] = r;
    }

    // ---- connectivity row (overwrites this wave's score row) --------------
    uint32_t mask = 0;
    #pragma unroll
    for (int e = 0; e < 16; ++e) {
        const int ix = ixs[e];
        const int lane_t = (ix >> 2) & 63;
        const int bitpos = ((ix >> 8) << 2) | (ix & 3);
        if (lane == lane_t) mask |= (1u << bitpos);
    }
    #pragma unroll
    for (int j = 0; j < 8; ++j) {
        float4 v;
        v.x = (mask >> (j * 4 + 0)) & 1u ? 1.f : 0.f;
        v.y = (mask >> (j * 4 + 1)) & 1u ? 1.f : 0.f;
        v.z = (mask >> (j * 4 + 2)) & 1u ? 1.f : 0.f;
        v.w = (mask >> (j * 4 + 3)) & 1u ? 1.f : 0.f;
        *(float4*)(srowp + j * 256 + lane * 4) = v;
    }

    // ---- edge rows: [sender_feat(128) | recv_feat(128)] -------------------
    const float* srow = S + (size_t)g * F;
    const float* rb = Rv + (size_t)bz * N * F;
    float4 vs = {0.f, 0.f, 0.f, 0.f};
    if (lane < 32) vs = *(const float4*)(srow + lane * 4);
    #pragma unroll
    for (int e = 0; e < 16; ++e) {
        float4 v = vs;
        if (lane >= 32)
            v = *(const float4*)(rb + (size_t)ixs[e] * F + (lane - 32) * 4);
        *(float4*)(edges_out + ((size_t)g * K_NE + rank[e]) * 256 + lane * 4) = v;
    }
}

extern "C" void kernel_launch(void* const* d_in, const int* in_sizes, int n_in,
                              void* d_out, int out_size, void* d_ws, size_t ws_size,
                              hipStream_t stream) {
    (void)in_sizes; (void)n_in; (void)out_size; (void)ws_size;
    const float* recv = (const float*)d_in[0];
    const float* send = (const float*)d_in[1];
    float* out = (float*)d_out;
    float* sender_mat = out + EDGE_FLOATS;       // score scratch, then conn matrix
    float* x2 = (float*)((char*)d_ws + (262144u * 4));
    float* y2 = x2 + NSEND;

    norms_kernel<<<4096, 256, 0, stream>>>(send, x2);
    norms_kernel<<<4096, 256, 0, stream>>>(recv, y2);
    dim3 g1(16, 16, 8);
    score_kernel<<<g1, 256, 0, stream>>>(send, recv, x2, y2, sender_mat);
    topk_fused_kernel<<<4096, 256, 0, stream>>>(send, recv, sender_mat, out);
}